// Round 1
// baseline (2528.930 us; speedup 1.0000x reference)
//
#include <hip/hip_runtime.h>
#include <math.h>

constexpr int N_NODES = 500000;
constexpr int N_EDGES = 16000000;

// ---------------------------------------------------------------------------
// ws layout (floats): [0,N) deg->dis (in place)  [N,2N) y=dis*x
//                     [2N,3N) inagg              [3N,4N) outco
//                     [4N,4N+2) global accumulators for s[k]
// total = 4*N*4 + 8 bytes ≈ 8 MB
// ---------------------------------------------------------------------------

__global__ __launch_bounds__(256) void k_init(float* __restrict__ deg,
                                              float* __restrict__ inagg,
                                              float* __restrict__ outco,
                                              float* __restrict__ sacc) {
    int i = blockIdx.x * blockDim.x + threadIdx.x;
    if (i < N_NODES) {
        deg[i]   = 1.0f;   // self-loop weight
        inagg[i] = 0.0f;
        outco[i] = 0.0f;
    }
    if (i < 2) sacc[i] = 0.0f;
}

// Edge pass A: in-degree (incl. edge weights). 4 edges/thread, 16B loads.
__global__ __launch_bounds__(256) void k_deg(const int4* __restrict__ dst4,
                                             const float4* __restrict__ w4,
                                             float* __restrict__ deg) {
    int i = blockIdx.x * blockDim.x + threadIdx.x;  // edge-quad index, grid covers exactly E/4
    int4   d = dst4[i];
    float4 w = w4[i];
    atomicAdd(&deg[d.x], w.x);
    atomicAdd(&deg[d.y], w.y);
    atomicAdd(&deg[d.z], w.z);
    atomicAdd(&deg[d.w], w.w);
}

// Node pass: dis = rsqrt(deg) (deg >= 1 always), y = dis * x
__global__ __launch_bounds__(256) void k_dis(float* __restrict__ degdis,
                                             const float* __restrict__ x,
                                             float* __restrict__ y) {
    int i = blockIdx.x * blockDim.x + threadIdx.x;
    if (i < N_NODES) {
        float d = rsqrtf(degdis[i]);
        degdis[i] = d;
        y[i] = d * x[i];
    }
}

// Edge pass B: inagg[dst] += w*y[src];  outco[src] += w*dis[dst]
__global__ __launch_bounds__(256) void k_edge2(const int4* __restrict__ src4,
                                               const int4* __restrict__ dst4,
                                               const float4* __restrict__ w4,
                                               const float* __restrict__ dis,
                                               const float* __restrict__ y,
                                               float* __restrict__ inagg,
                                               float* __restrict__ outco) {
    int i = blockIdx.x * blockDim.x + threadIdx.x;
    int4   s = src4[i];
    int4   d = dst4[i];
    float4 w = w4[i];
    // gathers: node arrays are 2 MB -> L2/L3 resident
    atomicAdd(&inagg[d.x], w.x * y[s.x]);
    atomicAdd(&inagg[d.y], w.y * y[s.y]);
    atomicAdd(&inagg[d.z], w.z * y[s.z]);
    atomicAdd(&inagg[d.w], w.w * y[s.w]);
    atomicAdd(&outco[s.x], w.x * dis[d.x]);
    atomicAdd(&outco[s.y], w.y * dis[d.y]);
    atomicAdd(&outco[s.z], w.z * dis[d.z]);
    atomicAdd(&outco[s.w], w.w * dis[d.w]);
}

// Node pass: per-node tiny MLP, weight by coef, reduce to 2 scalars.
__global__ __launch_bounds__(256) void k_node(const float* __restrict__ dis,
                                              const float* __restrict__ x,
                                              const float* __restrict__ inagg,
                                              const float* __restrict__ outco,
                                              const float* __restrict__ W1,
                                              const float* __restrict__ b1,
                                              const float* __restrict__ W2,
                                              float* __restrict__ sacc) {
    int i = blockIdx.x * blockDim.x + threadIdx.x;
    float c0 = 0.0f, c1 = 0.0f;
    if (i < N_NODES) {
        float dv   = dis[i];
        float agg1 = dv * (inagg[i] + dv * x[i]);        // layer-1 scalar pre-activation basis
        float coef = dv * outco[i] + dv * dv;            // layer-2 outgoing norm sum (+self-loop)
        float h0 = 0.0f, h1 = 0.0f;
#pragma unroll
        for (int j = 0; j < 16; ++j) {
            float a = fmaxf(agg1 * W1[j] + b1[j], 0.0f); // relu(out1[v,j])
            h0 = fmaf(a, W2[2 * j + 0], h0);
            h1 = fmaf(a, W2[2 * j + 1], h1);
        }
        c0 = coef * h0;
        c1 = coef * h1;
    }
    // wave64 butterfly reduce
#pragma unroll
    for (int off = 32; off > 0; off >>= 1) {
        c0 += __shfl_down(c0, off, 64);
        c1 += __shfl_down(c1, off, 64);
    }
    __shared__ float red0[4], red1[4];
    int wave = threadIdx.x >> 6;
    int lane = threadIdx.x & 63;
    if (lane == 0) { red0[wave] = c0; red1[wave] = c1; }
    __syncthreads();
    if (threadIdx.x == 0) {
        float t0 = red0[0] + red0[1] + red0[2] + red0[3];
        float t1 = red1[0] + red1[1] + red1[2] + red1[3];
        atomicAdd(&sacc[0], t0);
        atomicAdd(&sacc[1], t1);
    }
}

__global__ void k_final(const float* __restrict__ sacc,
                        const float* __restrict__ b2,
                        float* __restrict__ out) {
    if (threadIdx.x == 0 && blockIdx.x == 0) {
        float s0 = sacc[0] + (float)N_NODES * b2[0];
        float s1 = sacc[1] + (float)N_NODES * b2[1];
        float m  = fmaxf(s0, s1);
        float e0 = __expf(s0 - m);
        float e1 = __expf(s1 - m);
        float inv = 1.0f / (e0 + e1);
        out[0] = e0 * inv;
        out[1] = e1 * inv;
    }
}

extern "C" void kernel_launch(void* const* d_in, const int* in_sizes, int n_in,
                              void* d_out, int out_size, void* d_ws, size_t ws_size,
                              hipStream_t stream) {
    const float* x   = (const float*)d_in[0];
    const int*   ei  = (const int*)d_in[1];     // [2, E] int32
    const float* ew  = (const float*)d_in[2];
    const float* W1  = (const float*)d_in[3];   // [1,16]
    const float* b1  = (const float*)d_in[4];   // [16]
    const float* W2  = (const float*)d_in[5];   // [16,2]
    const float* b2  = (const float*)d_in[6];   // [2]
    float* out = (float*)d_out;

    const int* src = ei;
    const int* dst = ei + N_EDGES;

    float* ws     = (float*)d_ws;
    float* degdis = ws;                 // N: deg, then dis in place
    float* y      = ws + N_NODES;       // N
    float* inagg  = ws + 2 * N_NODES;   // N
    float* outco  = ws + 3 * N_NODES;   // N
    float* sacc   = ws + 4 * N_NODES;   // 2

    const int TB = 256;
    const int nodeBlocks = (N_NODES + TB - 1) / TB;       // 1954
    const int edgeQuads  = N_EDGES / 4;                   // 4,000,000
    const int edgeBlocks = edgeQuads / TB;                // 15625 exactly

    k_init<<<nodeBlocks, TB, 0, stream>>>(degdis, inagg, outco, sacc);
    k_deg<<<edgeBlocks, TB, 0, stream>>>((const int4*)dst, (const float4*)ew, degdis);
    k_dis<<<nodeBlocks, TB, 0, stream>>>(degdis, x, y);
    k_edge2<<<edgeBlocks, TB, 0, stream>>>((const int4*)src, (const int4*)dst,
                                           (const float4*)ew, degdis, y, inagg, outco);
    k_node<<<nodeBlocks, TB, 0, stream>>>(degdis, x, inagg, outco, W1, b1, W2, sacc);
    k_final<<<1, 64, 0, stream>>>(sacc, b2, out);
}

// Round 2
// 2528.331 us; speedup vs baseline: 1.0002x; 1.0002x over previous
//
#include <hip/hip_runtime.h>
#include <math.h>

constexpr int N_NODES = 500000;
constexpr int N_EDGES = 16000000;

// ---------------------------------------------------------------------------
// ws layout (floats): [0,N) deg->dis (in place)  [N,2N) y=dis*x
//                     [2N,3N) inagg              [3N,4N) outco
//                     [4N,4N+2) global accumulators for s[k]
// total = 4*N*4 + 8 bytes ≈ 8 MB
//
// All edge scatters use unsafeAtomicAdd -> HW global_atomic_add_f32
// (fire-and-forget, no CAS loop). d_ws is hipMalloc'd (coarse-grained), so
// the HW fp32 atomic is valid there.
// ---------------------------------------------------------------------------

__global__ __launch_bounds__(256) void k_init(float* __restrict__ deg,
                                              float* __restrict__ inagg,
                                              float* __restrict__ outco,
                                              float* __restrict__ sacc) {
    int i = blockIdx.x * blockDim.x + threadIdx.x;
    if (i < N_NODES) {
        deg[i]   = 1.0f;   // self-loop weight
        inagg[i] = 0.0f;
        outco[i] = 0.0f;
    }
    if (i < 2) sacc[i] = 0.0f;
}

// Edge pass A: in-degree (incl. edge weights). 4 edges/thread, 16B loads.
__global__ __launch_bounds__(256) void k_deg(const int4* __restrict__ dst4,
                                             const float4* __restrict__ w4,
                                             float* __restrict__ deg) {
    int i = blockIdx.x * blockDim.x + threadIdx.x;  // edge-quad index, grid covers exactly E/4
    int4   d = dst4[i];
    float4 w = w4[i];
    unsafeAtomicAdd(&deg[d.x], w.x);
    unsafeAtomicAdd(&deg[d.y], w.y);
    unsafeAtomicAdd(&deg[d.z], w.z);
    unsafeAtomicAdd(&deg[d.w], w.w);
}

// Node pass: dis = rsqrt(deg) (deg >= 1 always), y = dis * x
__global__ __launch_bounds__(256) void k_dis(float* __restrict__ degdis,
                                             const float* __restrict__ x,
                                             float* __restrict__ y) {
    int i = blockIdx.x * blockDim.x + threadIdx.x;
    if (i < N_NODES) {
        float d = rsqrtf(degdis[i]);
        degdis[i] = d;
        y[i] = d * x[i];
    }
}

// Edge pass B: inagg[dst] += w*y[src];  outco[src] += w*dis[dst]
__global__ __launch_bounds__(256) void k_edge2(const int4* __restrict__ src4,
                                               const int4* __restrict__ dst4,
                                               const float4* __restrict__ w4,
                                               const float* __restrict__ dis,
                                               const float* __restrict__ y,
                                               float* __restrict__ inagg,
                                               float* __restrict__ outco) {
    int i = blockIdx.x * blockDim.x + threadIdx.x;
    int4   s = src4[i];
    int4   d = dst4[i];
    float4 w = w4[i];
    // gathers: node arrays are 2 MB -> L2/L3 resident
    unsafeAtomicAdd(&inagg[d.x], w.x * y[s.x]);
    unsafeAtomicAdd(&inagg[d.y], w.y * y[s.y]);
    unsafeAtomicAdd(&inagg[d.z], w.z * y[s.z]);
    unsafeAtomicAdd(&inagg[d.w], w.w * y[s.w]);
    unsafeAtomicAdd(&outco[s.x], w.x * dis[d.x]);
    unsafeAtomicAdd(&outco[s.y], w.y * dis[d.y]);
    unsafeAtomicAdd(&outco[s.z], w.z * dis[d.z]);
    unsafeAtomicAdd(&outco[s.w], w.w * dis[d.w]);
}

// Node pass: per-node tiny MLP, weight by coef, reduce to 2 scalars.
__global__ __launch_bounds__(256) void k_node(const float* __restrict__ dis,
                                              const float* __restrict__ x,
                                              const float* __restrict__ inagg,
                                              const float* __restrict__ outco,
                                              const float* __restrict__ W1,
                                              const float* __restrict__ b1,
                                              const float* __restrict__ W2,
                                              float* __restrict__ sacc) {
    int i = blockIdx.x * blockDim.x + threadIdx.x;
    float c0 = 0.0f, c1 = 0.0f;
    if (i < N_NODES) {
        float dv   = dis[i];
        float agg1 = dv * (inagg[i] + dv * x[i]);        // layer-1 scalar pre-activation basis
        float coef = dv * outco[i] + dv * dv;            // layer-2 outgoing norm sum (+self-loop)
        float h0 = 0.0f, h1 = 0.0f;
#pragma unroll
        for (int j = 0; j < 16; ++j) {
            float a = fmaxf(agg1 * W1[j] + b1[j], 0.0f); // relu(out1[v,j])
            h0 = fmaf(a, W2[2 * j + 0], h0);
            h1 = fmaf(a, W2[2 * j + 1], h1);
        }
        c0 = coef * h0;
        c1 = coef * h1;
    }
    // wave64 butterfly reduce
#pragma unroll
    for (int off = 32; off > 0; off >>= 1) {
        c0 += __shfl_down(c0, off, 64);
        c1 += __shfl_down(c1, off, 64);
    }
    __shared__ float red0[4], red1[4];
    int wave = threadIdx.x >> 6;
    int lane = threadIdx.x & 63;
    if (lane == 0) { red0[wave] = c0; red1[wave] = c1; }
    __syncthreads();
    if (threadIdx.x == 0) {
        float t0 = red0[0] + red0[1] + red0[2] + red0[3];
        float t1 = red1[0] + red1[1] + red1[2] + red1[3];
        unsafeAtomicAdd(&sacc[0], t0);
        unsafeAtomicAdd(&sacc[1], t1);
    }
}

__global__ void k_final(const float* __restrict__ sacc,
                        const float* __restrict__ b2,
                        float* __restrict__ out) {
    if (threadIdx.x == 0 && blockIdx.x == 0) {
        float s0 = sacc[0] + (float)N_NODES * b2[0];
        float s1 = sacc[1] + (float)N_NODES * b2[1];
        float m  = fmaxf(s0, s1);
        float e0 = __expf(s0 - m);
        float e1 = __expf(s1 - m);
        float inv = 1.0f / (e0 + e1);
        out[0] = e0 * inv;
        out[1] = e1 * inv;
    }
}

extern "C" void kernel_launch(void* const* d_in, const int* in_sizes, int n_in,
                              void* d_out, int out_size, void* d_ws, size_t ws_size,
                              hipStream_t stream) {
    const float* x   = (const float*)d_in[0];
    const int*   ei  = (const int*)d_in[1];     // [2, E] int32
    const float* ew  = (const float*)d_in[2];
    const float* W1  = (const float*)d_in[3];   // [1,16]
    const float* b1  = (const float*)d_in[4];   // [16]
    const float* W2  = (const float*)d_in[5];   // [16,2]
    const float* b2  = (const float*)d_in[6];   // [2]
    float* out = (float*)d_out;

    const int* src = ei;
    const int* dst = ei + N_EDGES;

    float* ws     = (float*)d_ws;
    float* degdis = ws;                 // N: deg, then dis in place
    float* y      = ws + N_NODES;       // N
    float* inagg  = ws + 2 * N_NODES;   // N
    float* outco  = ws + 3 * N_NODES;   // N
    float* sacc   = ws + 4 * N_NODES;   // 2

    const int TB = 256;
    const int nodeBlocks = (N_NODES + TB - 1) / TB;       // 1954
    const int edgeQuads  = N_EDGES / 4;                   // 4,000,000
    const int edgeBlocks = edgeQuads / TB;                // 15625 exactly

    k_init<<<nodeBlocks, TB, 0, stream>>>(degdis, inagg, outco, sacc);
    k_deg<<<edgeBlocks, TB, 0, stream>>>((const int4*)dst, (const float4*)ew, degdis);
    k_dis<<<nodeBlocks, TB, 0, stream>>>(degdis, x, y);
    k_edge2<<<edgeBlocks, TB, 0, stream>>>((const int4*)src, (const int4*)dst,
                                           (const float4*)ew, degdis, y, inagg, outco);
    k_node<<<nodeBlocks, TB, 0, stream>>>(degdis, x, inagg, outco, W1, b1, W2, sacc);
    k_final<<<1, 64, 0, stream>>>(sacc, b2, out);
}